// Round 9
// baseline (177.421 us; speedup 1.0000x reference)
//
#include <hip/hip_runtime.h>
#include <stdint.h>

// QuantizedLinear: out[M,N] = (x[M,K] @ Wq^T) * scale[N] + bias[N]
// M = B*S = 4096, K = IN = 4096, N = OUT = 4096.
// Round 9: R6's proven loop (best measured: 125.8us, 1 barrier/tile, 3-buffer,
// counted vmcnt(4)) with ONE change: 32x32x16 f16 MFMA (2495 vs 2075 TF
// ceiling, half the instructions, same LDS traffic). Pre-tiled planes and
// staging identical; only fragment offsets, MFMA shape, epilogue map change.

#define M_DIM 4096
#define N_DIM 4096
#define K_DIM 4096
#define BM 256
#define BN 256
#define BK 32
#define KT_N (K_DIM / BK)      // 128 K-tiles
#define TILE_SHORTS 8192       // one 256xBK f16 tile = 16 KB
#define BUF_SHORTS 16384       // A tile + B tile = 32 KB
#define B_OFF 8192

typedef _Float16 f16x8 __attribute__((ext_vector_type(8)));
typedef __bf16   bf16x8v __attribute__((ext_vector_type(8)));
typedef float    f32x4  __attribute__((ext_vector_type(4)));
typedef float    f32x16 __attribute__((ext_vector_type(16)));

__device__ __forceinline__ unsigned short f32_f16_bits(float f) {
    _Float16 h = (_Float16)f;
    return __builtin_bit_cast(unsigned short, h);
}

__device__ __forceinline__ void gld16(const unsigned short* g, unsigned short* l) {
    __builtin_amdgcn_global_load_lds(
        (const __attribute__((address_space(1))) unsigned int*)g,
        (__attribute__((address_space(3))) unsigned int*)l,
        16, 0, 0);
}

// ---------- pre-pass: x (f32) -> f16 plane, TILED layout ----------
// AT: [mi(16)][kt(128)] tiles of [k8seg(4)][r(256)][8]  (exact BMxBK LDS image)
__global__ __launch_bounds__(256) void cvt_x_f16(const float* __restrict__ x,
                                                 unsigned short* __restrict__ AT) {
    const int b  = blockIdx.x;        // 16 * 128 = 2048
    const int mi = b >> 7;
    const int kt = b & 127;
    const int r  = threadIdx.x;       // 0..255

    const float* xp = x + (size_t)(mi * 256 + r) * K_DIM + kt * 32;
    unsigned short hh[32];
    #pragma unroll
    for (int j4 = 0; j4 < 8; ++j4) {
        float4 v = *(const float4*)(xp + j4 * 4);
        hh[j4*4+0] = f32_f16_bits(v.x);
        hh[j4*4+1] = f32_f16_bits(v.y);
        hh[j4*4+2] = f32_f16_bits(v.z);
        hh[j4*4+3] = f32_f16_bits(v.w);
    }
    unsigned short* o = AT + (size_t)(mi * KT_N + kt) * TILE_SHORTS + r * 8;
    #pragma unroll
    for (int ks = 0; ks < 4; ++ks) {
        uint4 p;
        p.x = (unsigned)hh[ks*8+0] | ((unsigned)hh[ks*8+1] << 16);
        p.y = (unsigned)hh[ks*8+2] | ((unsigned)hh[ks*8+3] << 16);
        p.z = (unsigned)hh[ks*8+4] | ((unsigned)hh[ks*8+5] << 16);
        p.w = (unsigned)hh[ks*8+6] | ((unsigned)hh[ks*8+7] << 16);
        *(uint4*)(o + ks * 2048) = p;     // (ks*256 + r)*8
    }
}

// ---------- pre-pass: Wq (int) -> f16 plane (exact), TILED layout ----------
__global__ __launch_bounds__(256) void cvt_w_f16(const int* __restrict__ wq,
                                                 unsigned short* __restrict__ BT) {
    const int b  = blockIdx.x;        // 16 * 128 = 2048
    const int ni = b >> 7;
    const int kt = b & 127;
    const int c  = threadIdx.x;       // 0..255

    const int* wp = wq + (size_t)(ni * 256 + c) * K_DIM + kt * 32;
    unsigned short bb[32];
    #pragma unroll
    for (int j4 = 0; j4 < 8; ++j4) {
        int4 v = *(const int4*)(wp + j4 * 4);
        bb[j4*4+0] = f32_f16_bits((float)v.x);
        bb[j4*4+1] = f32_f16_bits((float)v.y);
        bb[j4*4+2] = f32_f16_bits((float)v.z);
        bb[j4*4+3] = f32_f16_bits((float)v.w);
    }
    unsigned short* ob = BT + (size_t)(ni * KT_N + kt) * TILE_SHORTS + c * 8;
    #pragma unroll
    for (int ks = 0; ks < 4; ++ks) {
        uint4 p;
        p.x = (unsigned)bb[ks*8+0] | ((unsigned)bb[ks*8+1] << 16);
        p.y = (unsigned)bb[ks*8+2] | ((unsigned)bb[ks*8+3] << 16);
        p.z = (unsigned)bb[ks*8+4] | ((unsigned)bb[ks*8+5] << 16);
        p.w = (unsigned)bb[ks*8+6] | ((unsigned)bb[ks*8+7] << 16);
        *(uint4*)(ob + ks * 2048) = p;    // (ks*256 + c)*8
    }
}

// ---------- pipelined GEMM: 256x256, BK=32, 8 waves (128x64 each), 32x32x16 MFMA ----------
__global__ __launch_bounds__(512, 2) void gemm_pipe(
    const unsigned short* __restrict__ AT,
    const unsigned short* __restrict__ BT,
    const float* __restrict__ scale, const float* __restrict__ bias,
    float* __restrict__ out)
{
    __shared__ unsigned short lds[3 * BUF_SHORTS];   // 96 KB -> 1 block/CU

    const int t    = threadIdx.x;
    const int lane = t & 63;
    const int wid  = t >> 6;
    const int wr   = wid >> 2;       // 0..1  (128-row slab)
    const int wc   = wid & 3;        // 0..3  (64-col slab)
    const int ln31 = lane & 31;
    const int g    = lane >> 5;      // k8-segment within a K=16 slice

    // XCD swizzle: 256 blocks, 256 % 8 == 0 -> bijective
    const int bid = blockIdx.x;
    const int swz = (bid & 7) * 32 + (bid >> 3);
    const int mi  = swz & 15;
    const int ni  = swz >> 4;

    // staging: tiles are exact LDS images; thread t owns 16B chunks t and t+512
    const int lb0 = (t & ~63) * 8;           // wave-uniform LDS base (shorts)
    const int lb1 = lb0 + 4096;
    const unsigned short* gA = AT + (size_t)mi * KT_N * TILE_SHORTS + t * 8;
    const unsigned short* gB = BT + (size_t)ni * KT_N * TILE_SHORTS + t * 8;

#define STAGE(bufbase, kt) do { \
    gld16(gA + (size_t)(kt) * TILE_SHORTS,        lds + (bufbase) + lb0); \
    gld16(gA + (size_t)(kt) * TILE_SHORTS + 4096, lds + (bufbase) + lb1); \
    gld16(gB + (size_t)(kt) * TILE_SHORTS,        lds + (bufbase) + B_OFF + lb0); \
    gld16(gB + (size_t)(kt) * TILE_SHORTS + 4096, lds + (bufbase) + B_OFF + lb1); \
} while (0)

    // 32x32x16 fragment offsets (shorts). A: lane holds row=ln31 of its
    // 32-row tile, k = g*8 + e within K-slice s. LDS image row index =
    // (s*2+g)*256 + global_row; tile layout [4][256][8] reinterpreted as
    // [slice(2)][kseg(2)][row(256)][8] -- same bytes as the 16x16 layout.
    int offA[2][4], offB[2][2];
    #pragma unroll
    for (int s = 0; s < 2; ++s) {
        #pragma unroll
        for (int ti = 0; ti < 4; ++ti)
            offA[s][ti] = ((s * 2 + g) * 256 + wr * 128 + ti * 32 + ln31) * 8;
        #pragma unroll
        for (int tj = 0; tj < 2; ++tj)
            offB[s][tj] = B_OFF + ((s * 2 + g) * 256 + wc * 64 + tj * 32 + ln31) * 8;
    }

    f32x16 acc[4][2];
    #pragma unroll
    for (int ti = 0; ti < 4; ++ti)
        #pragma unroll
        for (int tj = 0; tj < 2; ++tj)
            acc[ti][tj] = (f32x16)(0.f);

    // prologue: tiles 0,1 -> buffers 0,1; counted: tile 0 landed, tile 1 in flight
    STAGE(0, 0);
    STAGE(BUF_SHORTS, 1);
    asm volatile("s_waitcnt vmcnt(4)" ::: "memory");
    __builtin_amdgcn_s_barrier();

    int curB = 0;
    int preB = 2 * BUF_SHORTS;

    for (int kt = 0; kt < KT_N; ++kt) {
        const unsigned short* Lb = lds + curB;

        f16x8 aF[2][4], bF[2][2];
        #pragma unroll
        for (int s = 0; s < 2; ++s) {
            #pragma unroll
            for (int tj = 0; tj < 2; ++tj) bF[s][tj] = *(const f16x8*)(Lb + offB[s][tj]);
            #pragma unroll
            for (int ti = 0; ti < 4; ++ti) aF[s][ti] = *(const f16x8*)(Lb + offA[s][ti]);
        }

        if (kt + 2 < KT_N) STAGE(preB, kt + 2);   // 2-deep prefetch

        asm volatile("s_waitcnt lgkmcnt(0)" ::: "memory");
        __builtin_amdgcn_sched_barrier(0);
        __builtin_amdgcn_s_setprio(1);
        #pragma unroll
        for (int s = 0; s < 2; ++s)
            #pragma unroll
            for (int ti = 0; ti < 4; ++ti)
                #pragma unroll
                for (int tj = 0; tj < 2; ++tj)
                    acc[ti][tj] = __builtin_amdgcn_mfma_f32_32x32x16_f16(
                        aF[s][ti], bF[s][tj], acc[ti][tj], 0, 0, 0);
        __builtin_amdgcn_s_setprio(0);

        // counted: tile kt+1's 4 loads landed; kt+2's 4 stay in flight
        if (kt + 2 < KT_N) asm volatile("s_waitcnt vmcnt(4)" ::: "memory");
        else               asm volatile("s_waitcnt vmcnt(0)" ::: "memory");
        __builtin_amdgcn_s_barrier();

        curB = (curB == 2 * BUF_SHORTS) ? 0 : curB + BUF_SHORTS;
        preB = (preB == 2 * BUF_SHORTS) ? 0 : preB + BUF_SHORTS;
    }
#undef STAGE

    // epilogue: 32x32 C/D layout (m74/m101-verified):
    // col = lane&31, row = (r&3) + 8*(r>>2) + 4*(lane>>5), r in [0,16)
    #pragma unroll
    for (int tj = 0; tj < 2; ++tj) {
        const int col = ni * BN + wc * 64 + tj * 32 + ln31;
        const float sc = scale[col];
        const float bi = bias[col];
        #pragma unroll
        for (int ti = 0; ti < 4; ++ti) {
            const int rbase = mi * BM + wr * 128 + ti * 32 + 4 * g;
            #pragma unroll
            for (int r = 0; r < 16; ++r) {
                const int row = rbase + (r & 3) + 8 * (r >> 2);
                out[(size_t)row * N_DIM + col] = acc[ti][tj][r] * sc + bi;
            }
        }
    }
}

// ---------- fallback (ws too small): reg-staged 2-plane bf16, proven structure ----------
__device__ __forceinline__ unsigned short f32_bf16_rne(float f) {
    unsigned u = __float_as_uint(f);
    u += 0x7FFFu + ((u >> 16) & 1u);
    return (unsigned short)(u >> 16);
}

__device__ __forceinline__ void cvt2(float a, float b, unsigned& hi2, unsigned& lo2) {
    unsigned short ha = f32_bf16_rne(a), hb = f32_bf16_rne(b);
    float fa = __uint_as_float((unsigned)ha << 16);
    float fb = __uint_as_float((unsigned)hb << 16);
    unsigned short la = f32_bf16_rne(a - fa), lb = f32_bf16_rne(b - fb);
    hi2 = (unsigned)ha | ((unsigned)hb << 16);
    lo2 = (unsigned)la | ((unsigned)lb << 16);
}

__global__ __launch_bounds__(256) void gemm_fb(
    const float* __restrict__ X, const int* __restrict__ Wq,
    const float* __restrict__ scale, const float* __restrict__ bias,
    float* __restrict__ out)
{
    __shared__ unsigned short sAh[4 * 128 * 8];
    __shared__ unsigned short sAl[4 * 128 * 8];
    __shared__ unsigned short sB [4 * 128 * 8];

    const int t    = threadIdx.x;
    const int lane = t & 63;
    const int wid  = t >> 6;
    const int brow = blockIdx.y * 128;
    const int bcol = blockIdx.x * 128;

    const int c1 = t,        c2 = t + 256;
    const int r1 = c1 & 127, s1 = c1 >> 7;
    const int r2 = c2 & 127, s2 = c2 >> 7;

    const int wr  = wid >> 1, wc = wid & 1;
    const int lr  = lane & 15;
    const int ksf = lane >> 4;

    f32x4 acc[4][4];
    #pragma unroll
    for (int m = 0; m < 4; ++m)
        #pragma unroll
        for (int n = 0; n < 4; ++n)
            acc[m][n] = (f32x4){0.f, 0.f, 0.f, 0.f};

    for (int k0 = 0; k0 < K_DIM; k0 += 32) {
        #pragma unroll
        for (int cc = 0; cc < 2; ++cc) {
            const int c = cc ? c2 : c1;
            const int r = cc ? r2 : r1;
            const int s = cc ? s2 : s1;
            const float* xa = X + (size_t)(brow + r) * K_DIM + k0 + s * 8;
            float4 v0 = *(const float4*)(xa);
            float4 v1 = *(const float4*)(xa + 4);
            uint4 hv, lv;
            cvt2(v0.x, v0.y, hv.x, lv.x);
            cvt2(v0.z, v0.w, hv.y, lv.y);
            cvt2(v1.x, v1.y, hv.z, lv.z);
            cvt2(v1.z, v1.w, hv.w, lv.w);
            *(uint4*)(sAh + c * 8) = hv;
            *(uint4*)(sAl + c * 8) = lv;

            const int* wa = Wq + (size_t)(bcol + r) * K_DIM + k0 + s * 8;
            int4 w0 = *(const int4*)(wa);
            int4 w1 = *(const int4*)(wa + 4);
            uint4 wv;
            wv.x = (unsigned)f32_bf16_rne((float)w0.x) | ((unsigned)f32_bf16_rne((float)w0.y) << 16);
            wv.y = (unsigned)f32_bf16_rne((float)w0.z) | ((unsigned)f32_bf16_rne((float)w0.w) << 16);
            wv.z = (unsigned)f32_bf16_rne((float)w1.x) | ((unsigned)f32_bf16_rne((float)w1.y) << 16);
            wv.w = (unsigned)f32_bf16_rne((float)w1.z) | ((unsigned)f32_bf16_rne((float)w1.w) << 16);
            *(uint4*)(sB + c * 8) = wv;
        }
        __syncthreads();

        bf16x8v ah[4], al[4], bb[4];
        #pragma unroll
        for (int m = 0; m < 4; ++m) {
            const int row = wr * 64 + m * 16 + lr;
            ah[m] = *(const bf16x8v*)(sAh + (ksf * 128 + row) * 8);
            al[m] = *(const bf16x8v*)(sAl + (ksf * 128 + row) * 8);
        }
        #pragma unroll
        for (int n = 0; n < 4; ++n) {
            const int row = wc * 64 + n * 16 + lr;
            bb[n] = *(const bf16x8v*)(sB + (ksf * 128 + row) * 8);
        }

        #pragma unroll
        for (int m = 0; m < 4; ++m)
            #pragma unroll
            for (int n = 0; n < 4; ++n) {
                acc[m][n] = __builtin_amdgcn_mfma_f32_16x16x32_bf16(ah[m], bb[n], acc[m][n], 0, 0, 0);
                acc[m][n] = __builtin_amdgcn_mfma_f32_16x16x32_bf16(al[m], bb[n], acc[m][n], 0, 0, 0);
            }
        __syncthreads();
    }

    #pragma unroll
    for (int n = 0; n < 4; ++n) {
        const int col = bcol + wc * 64 + n * 16 + lr;
        const float sc = scale[col];
        const float bi = bias[col];
        #pragma unroll
        for (int m = 0; m < 4; ++m) {
            const int r0 = brow + wr * 64 + m * 16 + ksf * 4;
            #pragma unroll
            for (int j = 0; j < 4; ++j)
                out[(size_t)(r0 + j) * N_DIM + col] = acc[m][n][j] * sc + bi;
        }
    }
}

extern "C" void kernel_launch(void* const* d_in, const int* in_sizes, int n_in,
                              void* d_out, int out_size, void* d_ws, size_t ws_size,
                              hipStream_t stream) {
    const float* x     = (const float*)d_in[0];
    const int*   wq    = (const int*)d_in[1];
    const float* scale = (const float*)d_in[2];
    const float* bias  = (const float*)d_in[3];
    float*       out   = (float*)d_out;

    const size_t planeElems = (size_t)M_DIM * K_DIM;        // 16,777,216
    const size_t planeBytes = planeElems * sizeof(unsigned short);  // 32 MiB

    if (ws_size >= 2 * planeBytes) {
        unsigned short* AT = (unsigned short*)d_ws;
        unsigned short* BT = AT + planeElems;
        cvt_x_f16<<<2048, 256, 0, stream>>>(x, AT);
        cvt_w_f16<<<2048, 256, 0, stream>>>(wq, BT);
        gemm_pipe<<<(M_DIM / BM) * (N_DIM / BN), 512, 0, stream>>>(AT, BT, scale, bias, out);
    } else {
        dim3 grid(N_DIM / 128, M_DIM / 128);
        gemm_fb<<<grid, 256, 0, stream>>>(x, wq, scale, bias, out);
    }
}

// Round 10
// 155.886 us; speedup vs baseline: 1.1381x; 1.1381x over previous
//
#include <hip/hip_runtime.h>
#include <stdint.h>

// QuantizedLinear: out[M,N] = (x[M,K] @ Wq^T) * scale[N] + bias[N]
// M = B*S = 4096, K = IN = 4096, N = OUT = 4096.
// Round 10: back to 16x16x32 f16, 256x256 tile, BK=32, 8 waves (128x64 each),
// 3 LDS buffers + counted vmcnt(4) -- R6's proven shell -- plus the ONE
// structural fix: one-tile REGISTER pipeline. Each iter issues tile kt's 12
// ds_reads (fragNext), stages tile kt+2, then runs tile kt-1's 32 MFMAs from
// fragPrev with NO waits: LDS reads drain under the MFMA cluster instead of
// serializing with it. lgkmcnt(0)+vmcnt(4) only at iter end (then barrier).

#define M_DIM 4096
#define N_DIM 4096
#define K_DIM 4096
#define BM 256
#define BN 256
#define BK 32
#define KT_N (K_DIM / BK)      // 128 K-tiles
#define TILE_SHORTS 8192       // one 256xBK f16 tile = 16 KB
#define BUF_SHORTS 16384       // A tile + B tile = 32 KB
#define B_OFF 8192

typedef _Float16 f16x8 __attribute__((ext_vector_type(8)));
typedef __bf16   bf16x8v __attribute__((ext_vector_type(8)));
typedef float    f32x4 __attribute__((ext_vector_type(4)));

__device__ __forceinline__ unsigned short f32_f16_bits(float f) {
    _Float16 h = (_Float16)f;
    return __builtin_bit_cast(unsigned short, h);
}

__device__ __forceinline__ void gld16(const unsigned short* g, unsigned short* l) {
    __builtin_amdgcn_global_load_lds(
        (const __attribute__((address_space(1))) unsigned int*)g,
        (__attribute__((address_space(3))) unsigned int*)l,
        16, 0, 0);
}

// ---------- pre-pass: x (f32) -> f16 plane, TILED layout ----------
// AT: [mi(16)][kt(128)] tiles of [ks(4)][r(256)][8]  (exact BMxBK LDS image)
__global__ __launch_bounds__(256) void cvt_x_f16(const float* __restrict__ x,
                                                 unsigned short* __restrict__ AT) {
    const int b  = blockIdx.x;        // 16 * 128 = 2048
    const int mi = b >> 7;
    const int kt = b & 127;
    const int r  = threadIdx.x;       // 0..255

    const float* xp = x + (size_t)(mi * 256 + r) * K_DIM + kt * 32;
    unsigned short hh[32];
    #pragma unroll
    for (int j4 = 0; j4 < 8; ++j4) {
        float4 v = *(const float4*)(xp + j4 * 4);
        hh[j4*4+0] = f32_f16_bits(v.x);
        hh[j4*4+1] = f32_f16_bits(v.y);
        hh[j4*4+2] = f32_f16_bits(v.z);
        hh[j4*4+3] = f32_f16_bits(v.w);
    }
    unsigned short* o = AT + (size_t)(mi * KT_N + kt) * TILE_SHORTS + r * 8;
    #pragma unroll
    for (int ks = 0; ks < 4; ++ks) {
        uint4 p;
        p.x = (unsigned)hh[ks*8+0] | ((unsigned)hh[ks*8+1] << 16);
        p.y = (unsigned)hh[ks*8+2] | ((unsigned)hh[ks*8+3] << 16);
        p.z = (unsigned)hh[ks*8+4] | ((unsigned)hh[ks*8+5] << 16);
        p.w = (unsigned)hh[ks*8+6] | ((unsigned)hh[ks*8+7] << 16);
        *(uint4*)(o + ks * 2048) = p;     // (ks*256 + r)*8
    }
}

// ---------- pre-pass: Wq (int) -> f16 plane (exact), TILED layout ----------
__global__ __launch_bounds__(256) void cvt_w_f16(const int* __restrict__ wq,
                                                 unsigned short* __restrict__ BT) {
    const int b  = blockIdx.x;        // 16 * 128 = 2048
    const int ni = b >> 7;
    const int kt = b & 127;
    const int c  = threadIdx.x;       // 0..255

    const int* wp = wq + (size_t)(ni * 256 + c) * K_DIM + kt * 32;
    unsigned short bb[32];
    #pragma unroll
    for (int j4 = 0; j4 < 8; ++j4) {
        int4 v = *(const int4*)(wp + j4 * 4);
        bb[j4*4+0] = f32_f16_bits((float)v.x);
        bb[j4*4+1] = f32_f16_bits((float)v.y);
        bb[j4*4+2] = f32_f16_bits((float)v.z);
        bb[j4*4+3] = f32_f16_bits((float)v.w);
    }
    unsigned short* ob = BT + (size_t)(ni * KT_N + kt) * TILE_SHORTS + c * 8;
    #pragma unroll
    for (int ks = 0; ks < 4; ++ks) {
        uint4 p;
        p.x = (unsigned)bb[ks*8+0] | ((unsigned)bb[ks*8+1] << 16);
        p.y = (unsigned)bb[ks*8+2] | ((unsigned)bb[ks*8+3] << 16);
        p.z = (unsigned)bb[ks*8+4] | ((unsigned)bb[ks*8+5] << 16);
        p.w = (unsigned)bb[ks*8+6] | ((unsigned)bb[ks*8+7] << 16);
        *(uint4*)(ob + ks * 2048) = p;    // (ks*256 + c)*8
    }
}

// ---------- pipelined GEMM with register read-ahead ----------
__global__ __launch_bounds__(512, 2) void gemm_pipe(
    const unsigned short* __restrict__ AT,
    const unsigned short* __restrict__ BT,
    const float* __restrict__ scale, const float* __restrict__ bias,
    float* __restrict__ out)
{
    __shared__ unsigned short lds[3 * BUF_SHORTS];   // 96 KB -> 1 block/CU

    const int t    = threadIdx.x;
    const int lane = t & 63;
    const int wid  = t >> 6;
    const int wr   = wid >> 2;       // 0..1  (128-row slab)
    const int wc   = wid & 3;        // 0..3  (64-col slab)
    const int lr   = lane & 15;
    const int ksf  = lane >> 4;

    // XCD swizzle: 256 blocks, 256 % 8 == 0 -> bijective
    const int bid = blockIdx.x;
    const int swz = (bid & 7) * 32 + (bid >> 3);
    const int mi  = swz & 15;
    const int ni  = swz >> 4;

    const int lb0 = (t & ~63) * 8;           // wave-uniform LDS base (shorts)
    const int lb1 = lb0 + 4096;
    const unsigned short* gA = AT + (size_t)mi * KT_N * TILE_SHORTS + t * 8;
    const unsigned short* gB = BT + (size_t)ni * KT_N * TILE_SHORTS + t * 8;

#define STAGE(bufbase, kt) do { \
    gld16(gA + (size_t)(kt) * TILE_SHORTS,        lds + (bufbase) + lb0); \
    gld16(gA + (size_t)(kt) * TILE_SHORTS + 4096, lds + (bufbase) + lb1); \
    gld16(gB + (size_t)(kt) * TILE_SHORTS,        lds + (bufbase) + B_OFF + lb0); \
    gld16(gB + (size_t)(kt) * TILE_SHORTS + 4096, lds + (bufbase) + B_OFF + lb1); \
} while (0)

    // fragment bases (shorts); per-frag deltas are compile-time immediates
    const int baseA = (ksf * 256 + wr * 128 + lr) * 8;          // + m*128
    const int baseB = B_OFF + (ksf * 256 + wc * 64 + lr) * 8;   // + n*128

    f32x4 acc[8][4];
    #pragma unroll
    for (int m = 0; m < 8; ++m)
        #pragma unroll
        for (int n = 0; n < 4; ++n)
            acc[m][n] = (f32x4){0.f, 0.f, 0.f, 0.f};

    f16x8 aE[8], bE[4], aO[8], bO[4];   // even/odd frag sets (static indexing)

    // one K-step: read frags(kt)->CUR, stage kt+2, MFMA(kt-1) from PRV, waits, barrier
#define KSTEP(kt, rB, sB, aCUR, bCUR, aPRV, bPRV) do {                        \
    const unsigned short* Lb = lds + (rB);                                    \
    _Pragma("unroll")                                                         \
    for (int n = 0; n < 4; ++n) bCUR[n] = *(const f16x8*)(Lb + baseB + n*128);\
    _Pragma("unroll")                                                         \
    for (int m = 0; m < 8; ++m) aCUR[m] = *(const f16x8*)(Lb + baseA + m*128);\
    if ((kt) + 2 < KT_N) STAGE((sB), (kt) + 2);                               \
    if ((kt) > 0) {                                                           \
        __builtin_amdgcn_s_setprio(1);                                        \
        _Pragma("unroll")                                                     \
        for (int m = 0; m < 8; ++m)                                           \
            _Pragma("unroll")                                                 \
            for (int n = 0; n < 4; ++n)                                       \
                acc[m][n] = __builtin_amdgcn_mfma_f32_16x16x32_f16(           \
                    aPRV[m], bPRV[n], acc[m][n], 0, 0, 0);                    \
        __builtin_amdgcn_s_setprio(0);                                        \
    }                                                                         \
    if ((kt) + 2 < KT_N) asm volatile("s_waitcnt vmcnt(4) lgkmcnt(0)" ::: "memory"); \
    else                 asm volatile("s_waitcnt vmcnt(0) lgkmcnt(0)" ::: "memory"); \
    __builtin_amdgcn_s_barrier();                                             \
} while (0)

    // prologue: stage tiles 0,1 into buffers 0,1; tile0 landed, tile1 in flight
    STAGE(0, 0);
    STAGE(BUF_SHORTS, 1);
    asm volatile("s_waitcnt vmcnt(4)" ::: "memory");
    __builtin_amdgcn_s_barrier();

    int rB = 0;                  // buffer holding tile kt
    int sB = 2 * BUF_SHORTS;     // buffer for tile kt+2
    for (int kt2 = 0; kt2 < KT_N; kt2 += 2) {
        KSTEP(kt2,     rB, sB, aE, bE, aO, bO);   // reads->even, MFMA from odd
        rB = (rB == 2*BUF_SHORTS) ? 0 : rB + BUF_SHORTS;
        sB = (sB == 2*BUF_SHORTS) ? 0 : sB + BUF_SHORTS;
        KSTEP(kt2 + 1, rB, sB, aO, bO, aE, bE);   // reads->odd, MFMA from even
        rB = (rB == 2*BUF_SHORTS) ? 0 : rB + BUF_SHORTS;
        sB = (sB == 2*BUF_SHORTS) ? 0 : sB + BUF_SHORTS;
    }
    // drain: MFMA for tile KT_N-1 (frags in odd set; reads drained at last KSTEP)
    __builtin_amdgcn_s_setprio(1);
    #pragma unroll
    for (int m = 0; m < 8; ++m)
        #pragma unroll
        for (int n = 0; n < 4; ++n)
            acc[m][n] = __builtin_amdgcn_mfma_f32_16x16x32_f16(aO[m], bO[n], acc[m][n], 0, 0, 0);
    __builtin_amdgcn_s_setprio(0);
#undef KSTEP
#undef STAGE

    // epilogue: C/D layout col=lane&15, row=(lane>>4)*4+j (m89-verified)
    #pragma unroll
    for (int n = 0; n < 4; ++n) {
        const int col = ni * BN + wc * 64 + n * 16 + lr;
        const float sc = scale[col];
        const float bi = bias[col];
        #pragma unroll
        for (int m = 0; m < 8; ++m) {
            const int r0 = mi * BM + wr * 128 + m * 16 + ksf * 4;
            #pragma unroll
            for (int j = 0; j < 4; ++j)
                out[(size_t)(r0 + j) * N_DIM + col] = acc[m][n][j] * sc + bi;
        }
    }
}

// ---------- fallback (ws too small): reg-staged 2-plane bf16, proven structure ----------
__device__ __forceinline__ unsigned short f32_bf16_rne(float f) {
    unsigned u = __float_as_uint(f);
    u += 0x7FFFu + ((u >> 16) & 1u);
    return (unsigned short)(u >> 16);
}

__device__ __forceinline__ void cvt2(float a, float b, unsigned& hi2, unsigned& lo2) {
    unsigned short ha = f32_bf16_rne(a), hb = f32_bf16_rne(b);
    float fa = __uint_as_float((unsigned)ha << 16);
    float fb = __uint_as_float((unsigned)hb << 16);
    unsigned short la = f32_bf16_rne(a - fa), lb = f32_bf16_rne(b - fb);
    hi2 = (unsigned)ha | ((unsigned)hb << 16);
    lo2 = (unsigned)la | ((unsigned)lb << 16);
}

__global__ __launch_bounds__(256) void gemm_fb(
    const float* __restrict__ X, const int* __restrict__ Wq,
    const float* __restrict__ scale, const float* __restrict__ bias,
    float* __restrict__ out)
{
    __shared__ unsigned short sAh[4 * 128 * 8];
    __shared__ unsigned short sAl[4 * 128 * 8];
    __shared__ unsigned short sB [4 * 128 * 8];

    const int t    = threadIdx.x;
    const int lane = t & 63;
    const int wid  = t >> 6;
    const int brow = blockIdx.y * 128;
    const int bcol = blockIdx.x * 128;

    const int c1 = t,        c2 = t + 256;
    const int r1 = c1 & 127, s1 = c1 >> 7;
    const int r2 = c2 & 127, s2 = c2 >> 7;

    const int wr  = wid >> 1, wc = wid & 1;
    const int lr  = lane & 15;
    const int ksf = lane >> 4;

    f32x4 acc[4][4];
    #pragma unroll
    for (int m = 0; m < 4; ++m)
        #pragma unroll
        for (int n = 0; n < 4; ++n)
            acc[m][n] = (f32x4){0.f, 0.f, 0.f, 0.f};

    for (int k0 = 0; k0 < K_DIM; k0 += 32) {
        #pragma unroll
        for (int cc = 0; cc < 2; ++cc) {
            const int c = cc ? c2 : c1;
            const int r = cc ? r2 : r1;
            const int s = cc ? s2 : s1;
            const float* xa = X + (size_t)(brow + r) * K_DIM + k0 + s * 8;
            float4 v0 = *(const float4*)(xa);
            float4 v1 = *(const float4*)(xa + 4);
            uint4 hv, lv;
            cvt2(v0.x, v0.y, hv.x, lv.x);
            cvt2(v0.z, v0.w, hv.y, lv.y);
            cvt2(v1.x, v1.y, hv.z, lv.z);
            cvt2(v1.z, v1.w, hv.w, lv.w);
            *(uint4*)(sAh + c * 8) = hv;
            *(uint4*)(sAl + c * 8) = lv;

            const int* wa = Wq + (size_t)(bcol + r) * K_DIM + k0 + s * 8;
            int4 w0 = *(const int4*)(wa);
            int4 w1 = *(const int4*)(wa + 4);
            uint4 wv;
            wv.x = (unsigned)f32_bf16_rne((float)w0.x) | ((unsigned)f32_bf16_rne((float)w0.y) << 16);
            wv.y = (unsigned)f32_bf16_rne((float)w0.z) | ((unsigned)f32_bf16_rne((float)w0.w) << 16);
            wv.z = (unsigned)f32_bf16_rne((float)w1.x) | ((unsigned)f32_bf16_rne((float)w1.y) << 16);
            wv.w = (unsigned)f32_bf16_rne((float)w1.z) | ((unsigned)f32_bf16_rne((float)w1.w) << 16);
            *(uint4*)(sB + c * 8) = wv;
        }
        __syncthreads();

        bf16x8v ah[4], al[4], bb[4];
        #pragma unroll
        for (int m = 0; m < 4; ++m) {
            const int row = wr * 64 + m * 16 + lr;
            ah[m] = *(const bf16x8v*)(sAh + (ksf * 128 + row) * 8);
            al[m] = *(const bf16x8v*)(sAl + (ksf * 128 + row) * 8);
        }
        #pragma unroll
        for (int n = 0; n < 4; ++n) {
            const int row = wc * 64 + n * 16 + lr;
            bb[n] = *(const bf16x8v*)(sB + (ksf * 128 + row) * 8);
        }

        #pragma unroll
        for (int m = 0; m < 4; ++m)
            #pragma unroll
            for (int n = 0; n < 4; ++n) {
                acc[m][n] = __builtin_amdgcn_mfma_f32_16x16x32_bf16(ah[m], bb[n], acc[m][n], 0, 0, 0);
                acc[m][n] = __builtin_amdgcn_mfma_f32_16x16x32_bf16(al[m], bb[n], acc[m][n], 0, 0, 0);
            }
        __syncthreads();
    }

    #pragma unroll
    for (int n = 0; n < 4; ++n) {
        const int col = bcol + wc * 64 + n * 16 + lr;
        const float sc = scale[col];
        const float bi = bias[col];
        #pragma unroll
        for (int m = 0; m < 4; ++m) {
            const int r0 = brow + wr * 64 + m * 16 + ksf * 4;
            #pragma unroll
            for (int j = 0; j < 4; ++j)
                out[(size_t)(r0 + j) * N_DIM + col] = acc[m][n][j] * sc + bi;
        }
    }
}

extern "C" void kernel_launch(void* const* d_in, const int* in_sizes, int n_in,
                              void* d_out, int out_size, void* d_ws, size_t ws_size,
                              hipStream_t stream) {
    const float* x     = (const float*)d_in[0];
    const int*   wq    = (const int*)d_in[1];
    const float* scale = (const float*)d_in[2];
    const float* bias  = (const float*)d_in[3];
    float*       out   = (float*)d_out;

    const size_t planeElems = (size_t)M_DIM * K_DIM;        // 16,777,216
    const size_t planeBytes = planeElems * sizeof(unsigned short);  // 32 MiB

    if (ws_size >= 2 * planeBytes) {
        unsigned short* AT = (unsigned short*)d_ws;
        unsigned short* BT = AT + planeElems;
        cvt_x_f16<<<2048, 256, 0, stream>>>(x, AT);
        cvt_w_f16<<<2048, 256, 0, stream>>>(wq, BT);
        gemm_pipe<<<(M_DIM / BM) * (N_DIM / BN), 512, 0, stream>>>(AT, BT, scale, bias, out);
    } else {
        dim3 grid(N_DIM / 128, M_DIM / 128);
        gemm_fb<<<grid, 256, 0, stream>>>(x, wq, scale, bias, out);
    }
}